// Round 2
// baseline (9241.055 us; speedup 1.0000x reference)
//
#include <hip/hip_runtime.h>
#include <cmath>

#define BATCH 16
#define NID   15
#define NSEG  (BATCH*NID)      // 240 segments (b, id)
#define HW    262144           // 512*512
#define SH    15               // bucket = float_bits >> 15  (~0.39% relative width)
#define NBUCK 32513            // (0x3F800000>>15)+1, covers d in [0,1]
#define NB1   (NBUCK+1)
#define SEGSTRIDE 130064       // ints per segment: Hp[NBUCK] Hn[NBUCK] PreP[NB1] PreN[NB1] (+pad)
#define NCH   16               // scan chunks per segment
#define CELEM 2048             // elements per scan chunk (256 thr * 8)
#define HEADB 65536            // head bytes: stats/derived/acc/partials

// identical expression in hist & query -> identical bucketing per element
__device__ __forceinline__ float dist_eval(float ex, float ey, float cx, float cy,
                                           float e0, float e1) {
  float dx = ex - cx;
  float dy = ey - cy;
  float arg = e0 * dx * dx + e1 * dy * dy;
  return expf(-arg);
}

// ---------------- per-(b,id) moment statistics + seed background ----------------
__global__ void stats_kernel(const float* __restrict__ pred, const int* __restrict__ inst,
                             const int* __restrict__ lab, float* __restrict__ stats,
                             float* __restrict__ seedbg) {
  __shared__ float ls[NID * 7 + 1];
  int tid = threadIdx.x;
  for (int i = tid; i < NID * 7 + 1; i += 256) ls[i] = 0.f;
  __syncthreads();
  int b = blockIdx.y;
  const float* pb = pred + (size_t)b * 5 * HW;
  for (int i = blockIdx.x * 256 + tid; i < HW; i += gridDim.x * 256) {
    float p0 = pb[i], p1 = pb[HW + i], p2 = pb[2 * HW + i], p3 = pb[3 * HW + i], p4 = pb[4 * HW + i];
    float xm = (float)(i & 511) * (1.0f / 511.0f);
    float ym = (float)(i >> 9) * (1.0f / 511.0f);
    float ex = tanhf(p0) + xm;
    float ey = tanhf(p1) + ym;
    int t = inst[(size_t)b * HW + i];
    if (t >= 1 && t <= NID) {
      float* s = ls + (t - 1) * 7;
      atomicAdd(s + 0, 1.0f);
      atomicAdd(s + 1, ex);
      atomicAdd(s + 2, ey);
      atomicAdd(s + 3, p2);
      atomicAdd(s + 4, p3);
      atomicAdd(s + 5, p2 * p2);
      atomicAdd(s + 6, p3 * p3);
    }
    if (lab[(size_t)b * HW + i] == 0) {
      float sd = 1.0f / (1.0f + expf(-p4));
      atomicAdd(&ls[NID * 7], sd * sd);
    }
  }
  __syncthreads();
  for (int i = tid; i < NID * 7; i += 256) {
    int id = i / 7, s = i % 7;
    atomicAdd(&stats[(b * NID + id) * 8 + s], ls[i]);
  }
  if (tid == 0) atomicAdd(&seedbg[b], ls[NID * 7]);
}

// ---------------- derived per-(b,id) params ----------------
__global__ void derived_kernel(const float* __restrict__ stats, float* __restrict__ derived) {
  int i = blockIdx.x * 256 + threadIdx.x;
  if (i >= NSEG) return;
  const float* st = stats + i * 8;
  float cnt = st[0];
  float safe = fmaxf(cnt, 1.0f);
  float cx = st[1] / safe, cy = st[2] / safe;
  float m0 = st[3] / safe, m1 = st[4] / safe;
  float v0 = st[5] - 2.0f * m0 * (m0 * safe) + m0 * m0 * cnt;
  float v1 = st[6] - 2.0f * m1 * (m1 * safe) + m1 * m1 * cnt;
  float vi = (v0 + v1) / (2.0f * safe);
  float* dd = derived + i * 8;
  dd[0] = cx;
  dd[1] = cy;
  dd[2] = expf(10.0f * m0);
  dd[3] = expf(10.0f * m1);
  dd[4] = vi;
  dd[5] = (cnt > 0.f) ? 1.f : 0.f;
  dd[6] = cnt;     // exact integer-valued float
  dd[7] = 0.f;
}

// ---------------- per-segment pos/neg bucket histograms + seed_i ----------------
__global__ void hist_kernel(const float* __restrict__ pred, const int* __restrict__ inst,
                            const float* __restrict__ derived, int* __restrict__ big,
                            float* __restrict__ seedi, int segBase) {
  int segLocal = blockIdx.y;
  int seg = segBase + segLocal;
  int b = seg / NID, n = seg % NID;
  __shared__ float prm[8];
  int tid = threadIdx.x;
  if (tid < 8) prm[tid] = derived[(size_t)seg * 8 + tid];
  __syncthreads();
  float acc = 0.f;
  if (prm[5] != 0.f) {
    int i = blockIdx.x * 256 + tid;   // grid.x*256 == HW
    const float* pb = pred + (size_t)b * 5 * HW;
    float p0 = pb[i], p1 = pb[HW + i];
    float xm = (float)(i & 511) * (1.0f / 511.0f);
    float ym = (float)(i >> 9) * (1.0f / 511.0f);
    float ex = tanhf(p0) + xm;
    float ey = tanhf(p1) + ym;
    float d = dist_eval(ex, ey, prm[0], prm[1], prm[2], prm[3]);
    unsigned key = __float_as_uint(d) >> SH;   // <= NBUCK-1 since d in (0,1]
    int t = inst[(size_t)b * HW + i];
    bool pos = (t == n + 1);
    int* base = big + (size_t)segLocal * SEGSTRIDE;
    atomicAdd(base + (pos ? 0 : NBUCK) + (int)key, 1);
    if (pos) {
      float p4 = pb[4 * HW + i];
      float sd = 1.0f / (1.0f + expf(-p4));
      float df = sd - d;
      acc = df * df;
    }
  }
  __shared__ float red[256];
  red[tid] = acc;
  __syncthreads();
  for (int s = 128; s > 0; s >>= 1) {
    if (tid < s) red[tid] += red[tid + s];
    __syncthreads();
  }
  if (tid == 0 && red[0] != 0.f) atomicAdd(&seedi[seg], red[0]);
}

// ---------------- scan phase 1: per-chunk partial sums (pos & neg) ----------------
__global__ void scan_p1(const int* __restrict__ big, int* __restrict__ partials, int nseg) {
  int segLocal = blockIdx.y;
  int c = blockIdx.x;
  const int* base = big + (size_t)segLocal * SEGSTRIDE;
  int tid = threadIdx.x;
  int start = c * CELEM + tid * 8;
  int sp = 0, sn = 0;
#pragma unroll
  for (int k = 0; k < 8; ++k) {
    int idx = start + k;
    if (idx < NBUCK) { sp += base[idx]; sn += base[NBUCK + idx]; }
  }
  __shared__ int red[256];
  red[tid] = sp;
  __syncthreads();
  for (int s = 128; s > 0; s >>= 1) { if (tid < s) red[tid] += red[tid + s]; __syncthreads(); }
  if (tid == 0) partials[segLocal * NCH + c] = red[0];
  __syncthreads();
  red[tid] = sn;
  __syncthreads();
  for (int s = 128; s > 0; s >>= 1) { if (tid < s) red[tid] += red[tid + s]; __syncthreads(); }
  if (tid == 0) partials[NSEG * NCH + segLocal * NCH + c] = red[0];
}

// ---------------- scan phase 2: exclusive scan of chunk partials ----------------
__global__ void scan_p2(int* __restrict__ partials, int* __restrict__ big, int nseg) {
  int sl = threadIdx.x;
  if (sl >= nseg) return;
  int* base = big + (size_t)sl * SEGSTRIDE;
  int* pp = partials + sl * NCH;
  int run = 0;
  for (int c = 0; c < NCH; ++c) { int v = pp[c]; pp[c] = run; run += v; }
  base[2 * NBUCK + NBUCK] = run;              // PreP[NBUCK] = P
  int* pn = partials + NSEG * NCH + sl * NCH;
  run = 0;
  for (int c = 0; c < NCH; ++c) { int v = pn[c]; pn[c] = run; run += v; }
  base[2 * NBUCK + NB1 + NBUCK] = run;        // PreN[NBUCK] = Nneg
}

// ---------------- scan phase 3: write PreP/PreN, zero Hn as rank counters ----------------
__global__ void scan_p3(int* __restrict__ big, const int* __restrict__ partials, int nseg) {
  int segLocal = blockIdx.y;
  int c = blockIdx.x;
  int tid = threadIdx.x;
  int* base = big + (size_t)segLocal * SEGSTRIDE;
  int* PreP = base + 2 * NBUCK;
  int* PreN = PreP + NB1;
  __shared__ int red[256];
  int start = c * CELEM + tid * 8;
  int pre[8];
  // positives
  int s = 0;
#pragma unroll
  for (int k = 0; k < 8; ++k) {
    int idx = start + k;
    int v = (idx < NBUCK) ? base[idx] : 0;
    pre[k] = s; s += v;
  }
  red[tid] = s;
  __syncthreads();
  for (int off = 1; off < 256; off <<= 1) {
    int v = red[tid]; int u = (tid >= off) ? red[tid - off] : 0;
    __syncthreads();
    red[tid] = v + u;
    __syncthreads();
  }
  int te = (tid > 0) ? red[tid - 1] : 0;
  int gb = partials[segLocal * NCH + c];
#pragma unroll
  for (int k = 0; k < 8; ++k) {
    int idx = start + k;
    if (idx < NBUCK) PreP[idx] = gb + te + pre[k];
  }
  __syncthreads();
  // negatives (and zero Hn -> rank counters)
  s = 0;
#pragma unroll
  for (int k = 0; k < 8; ++k) {
    int idx = start + k;
    int v = (idx < NBUCK) ? base[NBUCK + idx] : 0;
    pre[k] = s; s += v;
  }
  red[tid] = s;
  __syncthreads();
  for (int off = 1; off < 256; off <<= 1) {
    int v = red[tid]; int u = (tid >= off) ? red[tid - off] : 0;
    __syncthreads();
    red[tid] = v + u;
    __syncthreads();
  }
  te = (tid > 0) ? red[tid - 1] : 0;
  gb = partials[NSEG * NCH + segLocal * NCH + c];
#pragma unroll
  for (int k = 0; k < 8; ++k) {
    int idx = start + k;
    if (idx < NBUCK) { PreN[idx] = gb + te + pre[k]; base[NBUCK + idx] = 0; }
  }
}

// ---------------- Lovasz via prefix queries + interpolation + exact neg ranks ----------------
__global__ void query_kernel(const float* __restrict__ pred, const int* __restrict__ inst,
                             const float* __restrict__ derived, int* __restrict__ big,
                             float* __restrict__ instAcc, int segBase) {
  int segLocal = blockIdx.y;
  int seg = segBase + segLocal;
  int b = seg / NID, n = seg % NID;
  __shared__ float prm[8];
  int tid = threadIdx.x;
  if (tid < 8) prm[tid] = derived[(size_t)seg * 8 + tid];
  __syncthreads();
  float acc = 0.f;
  if (prm[5] != 0.f) {
    int* base = big + (size_t)segLocal * SEGSTRIDE;
    int* RankC = base + NBUCK;        // zeroed Hn reused as per-bucket rank counters
    int* PreP = base + 2 * NBUCK;
    int* PreN = PreP + NB1;
    int P = (int)prm[6];
    int NnegI = HW - P;
    int i = blockIdx.x * 256 + tid;
    const float* pb = pred + (size_t)b * 5 * HW;
    float p0 = pb[i], p1 = pb[HW + i];
    float xm = (float)(i & 511) * (1.0f / 511.0f);
    float ym = (float)(i >> 9) * (1.0f / 511.0f);
    float ex = tanhf(p0) + xm;
    float ey = tanhf(p1) + ym;
    float d = dist_eval(ex, ey, prm[0], prm[1], prm[2], prm[3]);
    float l = d * 2.0f - 1.0f;
    int t = inst[(size_t)b * HW + i];
    if (t == n + 1) {
      // positive: err a = 1-l; q = #neg{d' > 1-d}, boundary bucket interpolated
      float a = 1.0f - l;
      float tv = a * 0.5f;                        // = 1-d, in [0,1)
      int tb = (int)(__float_as_uint(tv) >> SH);
      int lo = PreN[tb], hi = PreN[tb + 1];
      float flo = __uint_as_float((unsigned)tb << SH);
      float fhi = __uint_as_float((unsigned)(tb + 1) << SH);
      float den = fhi - flo;
      float frac = (den > 0.f) ? (fhi - tv) / den : 0.5f;
      frac = fminf(fmaxf(frac, 0.f), 1.f);
      float q = (float)(NnegI - hi) + (float)(hi - lo) * frac;
      acc = a / ((float)P + q);
    } else {
      // negative: err bv = 1+l; p = #pos{d'' < 1-d} interpolated; exact rank via atomic
      float bv = 1.0f + l;
      float t2 = 1.0f - bv * 0.5f;                // in [0,1)
      int pbk = (int)(__float_as_uint(t2) >> SH);
      int plo = PreP[pbk], phi = PreP[pbk + 1];
      float flo = __uint_as_float((unsigned)pbk << SH);
      float fhi = __uint_as_float((unsigned)(pbk + 1) << SH);
      float den = fhi - flo;
      float frac = (den > 0.f) ? (t2 - flo) / den : 0.5f;
      frac = fminf(fmaxf(frac, 0.f), 1.f);
      float p = (float)plo + (float)(phi - plo) * frac;
      int mb = (int)(__float_as_uint(d) >> SH);
      int r = atomicAdd(&RankC[mb], 1);           // within-bucket rank (any order valid)
      int km1 = (NnegI - PreN[mb + 1]) + r;       // k-1 = #neg ranked above
      float u0 = 1.0f / (float)(P + km1);
      float u1 = 1.0f / (float)(P + km1 + 1);
      acc = bv * ((float)P - p) * (u0 - u1);
    }
  }
  __shared__ float redf[256];
  redf[tid] = acc;
  __syncthreads();
  for (int s = 128; s > 0; s >>= 1) {
    if (tid < s) redf[tid] += redf[tid + s];
    __syncthreads();
  }
  if (tid == 0) atomicAdd(&instAcc[seg], redf[0]);
}

// ---------------- final combine ----------------
__global__ void final_kernel(const float* __restrict__ derived, const float* __restrict__ instAcc,
                             const float* __restrict__ seediAcc, const float* __restrict__ seedbg,
                             float* __restrict__ out) {
  int b = threadIdx.x;
  __shared__ float red[64];
  float lb = 0.f;
  if (b < BATCH) {
    float sv = 0.f, si = 0.f, svar = 0.f, ssd = 0.f;
    for (int n = 0; n < NID; ++n) {
      const float* dd = derived + (b * NID + n) * 8;
      float vf = dd[5];
      sv += vf;
      si += vf * instAcc[b * NID + n];
      svar += vf * dd[4];
      ssd += vf * seediAcc[b * NID + n];
    }
    float obj = fmaxf(sv, 1.0f);
    lb = si / obj + 10.0f * (svar / obj) + (seedbg[b] + ssd) / (float)HW;
  }
  red[threadIdx.x] = lb;
  __syncthreads();
  for (int s = 32; s > 0; s >>= 1) {
    if (threadIdx.x < s) red[threadIdx.x] += red[threadIdx.x + s];
    __syncthreads();
  }
  if (threadIdx.x == 0) out[0] = red[0] / (float)BATCH;
}

extern "C" void kernel_launch(void* const* d_in, const int* in_sizes, int n_in,
                              void* d_out, int out_size, void* d_ws, size_t ws_size,
                              hipStream_t stream) {
  const float* pred = (const float*)d_in[0];
  const int* inst = (const int*)d_in[1];
  const int* lab = (const int*)d_in[2];
  float* out = (float*)d_out;

  // head layout (floats): stats[1920] derived[1920] instAcc[240] seediAcc[240] seedbg[16] | partials(int)
  float* wsf = (float*)d_ws;
  float* stats = wsf;
  float* derived = wsf + 1920;
  float* instAcc = wsf + 3840;
  float* seediAcc = wsf + 4080;
  float* seedbg = wsf + 4320;
  int* partials = (int*)(wsf + 4352);   // 2*NSEG*NCH = 7680 ints, ends well inside HEADB
  int* big = (int*)((char*)d_ws + HEADB);

  size_t avail = (ws_size > HEADB) ? (ws_size - HEADB) : 0;
  int chunkS = (int)(avail / ((size_t)SEGSTRIDE * 4));
  if (chunkS < 1) chunkS = 1;           // absolute floor: ~572 KB total
  if (chunkS > NSEG) chunkS = NSEG;

  hipMemsetAsync(d_ws, 0, HEADB, stream);
  stats_kernel<<<dim3(64, BATCH), 256, 0, stream>>>(pred, inst, lab, stats, seedbg);
  derived_kernel<<<1, 256, 0, stream>>>(stats, derived);

  for (int sb = 0; sb < NSEG; sb += chunkS) {
    int cn = NSEG - sb;
    if (cn > chunkS) cn = chunkS;
    hipMemsetAsync(big, 0, (size_t)cn * SEGSTRIDE * 4, stream);
    hist_kernel<<<dim3(HW / 256, cn), 256, 0, stream>>>(pred, inst, derived, big, seediAcc, sb);
    scan_p1<<<dim3(NCH, cn), 256, 0, stream>>>(big, partials, cn);
    scan_p2<<<1, 256, 0, stream>>>(partials, big, cn);
    scan_p3<<<dim3(NCH, cn), 256, 0, stream>>>(big, partials, cn);
    query_kernel<<<dim3(HW / 256, cn), 256, 0, stream>>>(pred, inst, derived, big, instAcc, sb);
  }
  final_kernel<<<1, 64, 0, stream>>>(derived, instAcc, seediAcc, seedbg, out);
}

// Round 3
// 464.210 us; speedup vs baseline: 19.9071x; 19.9071x over previous
//
#include <hip/hip_runtime.h>
#include <cmath>

#define BATCH 16
#define NID   15
#define NSEG  240
#define HW    262144          // 512*512
#define HEADB 65536

// compact key space for d = exp(-arg) in [0,1]:
//   d >= 2^-8 : fine buckets (float_bits>>15), 2305 keys, ~0.39% relative width
//   d <  2^-8 : exponent-only buckets (float_bits>>23), 119 keys (contributions negligible)
// keys ordered ascending in d.
#define KFINEBASE 30208       // 0x3B800000 >> 15
#define KOVF 119
#define KTOT 2424             // 119 + 2305

__device__ __forceinline__ int keyof(float d) {
  unsigned b = __float_as_uint(d);
  return (b >= 0x3B800000u) ? (int)((b >> 15) - KFINEBASE + KOVF) : (int)(b >> 23);
}
__device__ __forceinline__ void boundsof(int k, float* lo, float* hi) {
  if (k >= KOVF) {
    unsigned u = (unsigned)(k - KOVF + KFINEBASE) << 15;
    *lo = __uint_as_float(u);
    *hi = __uint_as_float(u + 32768u);
  } else {
    *lo = __uint_as_float((unsigned)k << 23);
    *hi = __uint_as_float((unsigned)(k + 1) << 23);
  }
}

// ---------------- precompute ex/ey/sd + per-(b,id) moment stats + seed bg ----------------
__global__ void pre_kernel(const float* __restrict__ pred, const int* __restrict__ inst,
                           const int* __restrict__ lab, float* __restrict__ stats,
                           float* __restrict__ seedbg, float2* __restrict__ exy,
                           float* __restrict__ sdv) {
  __shared__ float ls[NID * 7 + 1];
  int tid = threadIdx.x;
  for (int i = tid; i < NID * 7 + 1; i += 256) ls[i] = 0.f;
  __syncthreads();
  int b = blockIdx.y;
  const float* pb = pred + (size_t)b * 5 * HW;
  for (int i = blockIdx.x * 256 + tid; i < HW; i += gridDim.x * 256) {
    float p0 = pb[i], p1 = pb[HW + i], p2 = pb[2 * HW + i], p3 = pb[3 * HW + i], p4 = pb[4 * HW + i];
    float xm = (float)(i & 511) * (1.0f / 511.0f);
    float ym = (float)(i >> 9) * (1.0f / 511.0f);
    float ex = tanhf(p0) + xm;
    float ey = tanhf(p1) + ym;
    float sd = 1.0f / (1.0f + expf(-p4));
    exy[(size_t)b * HW + i] = make_float2(ex, ey);
    sdv[(size_t)b * HW + i] = sd;
    int t = inst[(size_t)b * HW + i];
    if (t >= 1 && t <= NID) {
      float* s = ls + (t - 1) * 7;
      atomicAdd(s + 0, 1.0f);
      atomicAdd(s + 1, ex);
      atomicAdd(s + 2, ey);
      atomicAdd(s + 3, p2);
      atomicAdd(s + 4, p3);
      atomicAdd(s + 5, p2 * p2);
      atomicAdd(s + 6, p3 * p3);
    }
    if (lab[(size_t)b * HW + i] == 0) atomicAdd(&ls[NID * 7], sd * sd);
  }
  __syncthreads();
  for (int i = tid; i < NID * 7; i += 256) {
    int id = i / 7, s = i % 7;
    atomicAdd(&stats[(b * NID + id) * 8 + s], ls[i]);
  }
  if (tid == 0) atomicAdd(&seedbg[b], ls[NID * 7]);
}

// ---------------- derived per-(b,id) params ----------------
__global__ void derived_kernel(const float* __restrict__ stats, float* __restrict__ derived) {
  int i = blockIdx.x * 256 + threadIdx.x;
  if (i >= NSEG) return;
  const float* st = stats + i * 8;
  float cnt = st[0];
  float safe = fmaxf(cnt, 1.0f);
  float cx = st[1] / safe, cy = st[2] / safe;
  float m0 = st[3] / safe, m1 = st[4] / safe;
  float v0 = st[5] - 2.0f * m0 * (m0 * safe) + m0 * m0 * cnt;
  float v1 = st[6] - 2.0f * m1 * (m1 * safe) + m1 * m1 * cnt;
  float vi = (v0 + v1) / (2.0f * safe);
  float* dd = derived + i * 8;
  dd[0] = cx;
  dd[1] = cy;
  dd[2] = expf(10.0f * m0);
  dd[3] = expf(10.0f * m1);
  dd[4] = vi;
  dd[5] = (cnt > 0.f) ? 1.f : 0.f;
  dd[6] = cnt;
  dd[7] = 0.f;
}

// ---------------- fused per-segment: LDS hist -> LDS scans -> bucket-sweep Lovasz ----------------
__global__ void __launch_bounds__(1024)
seg_kernel(const float2* __restrict__ exy, const float* __restrict__ sdv,
           const int* __restrict__ inst, const float* __restrict__ derived,
           float* __restrict__ instAcc, float* __restrict__ seedi) {
  __shared__ int histP[KTOT];
  __shared__ int histN[KTOT];
  __shared__ int PreP[KTOT + 1];
  __shared__ int PreN[KTOT + 1];
  __shared__ int scr[1024];
  __shared__ float prm[8];
  int seg = blockIdx.x;
  int b = seg / NID, n = seg % NID;
  int tid = threadIdx.x;
  if (tid < 8) prm[tid] = derived[(size_t)seg * 8 + tid];
  for (int k = tid; k < KTOT; k += 1024) { histP[k] = 0; histN[k] = 0; }
  __syncthreads();
  if (prm[5] == 0.f) {
    if (tid == 0) { instAcc[seg] = 0.f; seedi[seg] = 0.f; }
    return;
  }
  float cx = prm[0], cy = prm[1], e0 = prm[2], e1 = prm[3];
  int P = (int)prm[6];
  int Nn = HW - P;
  const float2* eb = exy + (size_t)b * HW;
  const float* sb = sdv + (size_t)b * HW;
  const int* ib = inst + (size_t)b * HW;
  float sacc = 0.f;
  // phase 1: LDS histogram (one LDS atomic per pixel) + seed accumulation
  for (int i = tid; i < HW; i += 1024) {
    float2 e = eb[i];
    int t = ib[i];
    float dx = e.x - cx;
    float dy = e.y - cy;
    float d = expf(-(e0 * dx * dx + e1 * dy * dy));
    int k = keyof(d);
    if (t == n + 1) {
      atomicAdd(&histP[k], 1);
      float df = sb[i] - d;
      sacc += df * df;
    } else {
      atomicAdd(&histN[k], 1);
    }
  }
  __syncthreads();
  // phase 2: exclusive prefix sums over keys (pos then neg)
  {
    int base = tid * 3;
    int a0 = (base < KTOT) ? histP[base] : 0;
    int a1 = (base + 1 < KTOT) ? histP[base + 1] : 0;
    int a2 = (base + 2 < KTOT) ? histP[base + 2] : 0;
    scr[tid] = a0 + a1 + a2;
    __syncthreads();
    for (int off = 1; off < 1024; off <<= 1) {
      int v = scr[tid];
      int u = (tid >= off) ? scr[tid - off] : 0;
      __syncthreads();
      scr[tid] = v + u;
      __syncthreads();
    }
    int excl = (tid > 0) ? scr[tid - 1] : 0;
    if (base < KTOT) PreP[base] = excl;
    if (base + 1 < KTOT) PreP[base + 1] = excl + a0;
    if (base + 2 < KTOT) PreP[base + 2] = excl + a0 + a1;
    if (tid == 0) PreP[KTOT] = scr[1023];
    __syncthreads();
    a0 = (base < KTOT) ? histN[base] : 0;
    a1 = (base + 1 < KTOT) ? histN[base + 1] : 0;
    a2 = (base + 2 < KTOT) ? histN[base + 2] : 0;
    scr[tid] = a0 + a1 + a2;
    __syncthreads();
    for (int off = 1; off < 1024; off <<= 1) {
      int v = scr[tid];
      int u = (tid >= off) ? scr[tid - off] : 0;
      __syncthreads();
      scr[tid] = v + u;
      __syncthreads();
    }
    excl = (tid > 0) ? scr[tid - 1] : 0;
    if (base < KTOT) PreN[base] = excl;
    if (base + 1 < KTOT) PreN[base + 1] = excl + a0;
    if (base + 2 < KTOT) PreN[base + 2] = excl + a0 + a1;
    if (tid == 0) PreN[KTOT] = scr[1023];
    __syncthreads();
  }
  // phase 3: per-bucket closed-form Lovasz contributions
  float acc = 0.f;
  for (int k = tid; k < KTOT; k += 1024) {
    int hp = histP[k], hn = histN[k];
    if ((hp | hn) == 0) continue;
    float lo, hi;
    boundsof(k, &lo, &hi);
    float m = 0.5f * (lo + hi);
    m = fminf(m, __uint_as_float(0x3F7FFFFFu));   // keep tv = 1-m > 0
    float tv = 1.0f - m;                          // mirror threshold
    int j = keyof(tv);
    float jlo, jhi;
    boundsof(j, &jlo, &jhi);
    float den = jhi - jlo;
    float fr = (den > 0.f) ? (tv - jlo) / den : 0.5f;
    fr = fminf(fmaxf(fr, 0.f), 1.f);
    if (hp) {
      // positives in bucket: err a = 2-2m; q = #neg{d' > 1-m} (interpolated)
      float q = (float)(Nn - PreN[j + 1]) + (1.0f - fr) * (float)histN[j];
      float a = 2.0f - 2.0f * m;
      acc += (float)hp * a / ((float)P + q);
    }
    if (hn) {
      // negatives: err b = 2m; p = #pos{d' < 1-m} (interpolated);
      // desc-ranks occupy (R, R+hn]; telescoped weight = 1/(P+R) - 1/(P+R+hn)
      float p = (float)PreP[j] + fr * (float)histP[j];
      int R = Nn - PreN[k + 1];
      float u0 = 1.0f / (float)(P + R);
      float u1 = 1.0f / (float)(P + R + hn);
      acc += (2.0f * m) * ((float)P - p) * (u0 - u1);
    }
  }
  // block reductions
  float* scrf = (float*)scr;
  scrf[tid] = acc;
  __syncthreads();
  for (int s = 512; s > 0; s >>= 1) {
    if (tid < s) scrf[tid] += scrf[tid + s];
    __syncthreads();
  }
  if (tid == 0) instAcc[seg] = scrf[0];
  __syncthreads();
  scrf[tid] = sacc;
  __syncthreads();
  for (int s = 512; s > 0; s >>= 1) {
    if (tid < s) scrf[tid] += scrf[tid + s];
    __syncthreads();
  }
  if (tid == 0) seedi[seg] = scrf[0];
}

// ---------------- final combine ----------------
__global__ void final_kernel(const float* __restrict__ derived, const float* __restrict__ instAcc,
                             const float* __restrict__ seediAcc, const float* __restrict__ seedbg,
                             float* __restrict__ out) {
  int b = threadIdx.x;
  __shared__ float red[64];
  float lb = 0.f;
  if (b < BATCH) {
    float sv = 0.f, si = 0.f, svar = 0.f, ssd = 0.f;
    for (int n = 0; n < NID; ++n) {
      const float* dd = derived + (b * NID + n) * 8;
      float vf = dd[5];
      sv += vf;
      si += vf * instAcc[b * NID + n];
      svar += vf * dd[4];
      ssd += vf * seediAcc[b * NID + n];
    }
    float obj = fmaxf(sv, 1.0f);
    lb = si / obj + 10.0f * (svar / obj) + (seedbg[b] + ssd) / (float)HW;
  }
  red[threadIdx.x] = lb;
  __syncthreads();
  for (int s = 32; s > 0; s >>= 1) {
    if (threadIdx.x < s) red[threadIdx.x] += red[threadIdx.x + s];
    __syncthreads();
  }
  if (threadIdx.x == 0) out[0] = red[0] / (float)BATCH;
}

extern "C" void kernel_launch(void* const* d_in, const int* in_sizes, int n_in,
                              void* d_out, int out_size, void* d_ws, size_t ws_size,
                              hipStream_t stream) {
  const float* pred = (const float*)d_in[0];
  const int* inst = (const int*)d_in[1];
  const int* lab = (const int*)d_in[2];
  float* out = (float*)d_out;

  // head (floats): stats[1920] derived[1920] instAcc[240] seedi[240] seedbg[16]
  float* wsf = (float*)d_ws;
  float* stats = wsf;
  float* derived = wsf + 1920;
  float* instAcc = wsf + 3840;
  float* seediAcc = wsf + 4080;
  float* seedbg = wsf + 4320;
  float2* exy = (float2*)((char*)d_ws + HEADB);                 // 16*HW*8B = 33.6 MB
  float* sdv = (float*)((char*)d_ws + HEADB + (size_t)BATCH * HW * 8);  // +16.8 MB

  hipMemsetAsync(d_ws, 0, HEADB, stream);
  pre_kernel<<<dim3(64, BATCH), 256, 0, stream>>>(pred, inst, lab, stats, seedbg, exy, sdv);
  derived_kernel<<<1, 256, 0, stream>>>(stats, derived);
  seg_kernel<<<NSEG, 1024, 0, stream>>>(exy, sdv, inst, derived, instAcc, seediAcc);
  final_kernel<<<1, 64, 0, stream>>>(derived, instAcc, seediAcc, seedbg, out);
}

// Round 4
// 403.087 us; speedup vs baseline: 22.9257x; 1.1516x over previous
//
#include <hip/hip_runtime.h>
#include <cmath>

#define BATCH 16
#define NID   15
#define NSEG  240
#define HW    262144          // 512*512
#define HEADB 65536
#define NSPL  4               // hist blocks per segment
#define S1T   512             // hist block threads

// compact key space for d = exp(-arg) in [0,1]:
//   d >= 2^-8 : fine buckets (float_bits>>15), 2305 keys, ~0.39% relative width
//   d <  2^-8 : exponent-only buckets (float_bits>>23), 119 keys
#define KFINEBASE 30208       // 0x3B800000 >> 15
#define KOVF 119
#define KTOT 2424             // 119 + 2305

__device__ __forceinline__ int keyof(float d) {
  unsigned b = __float_as_uint(d);
  return (b >= 0x3B800000u) ? (int)((b >> 15) - KFINEBASE + KOVF) : (int)(b >> 23);
}
__device__ __forceinline__ void boundsof(int k, float* lo, float* hi) {
  if (k >= KOVF) {
    unsigned u = (unsigned)(k - KOVF + KFINEBASE) << 15;
    *lo = __uint_as_float(u);
    *hi = __uint_as_float(u + 32768u);
  } else {
    *lo = __uint_as_float((unsigned)k << 23);
    *hi = __uint_as_float((unsigned)(k + 1) << 23);
  }
}

// ---------------- precompute ex/ey + per-(b,id) moment stats + seed bg ----------------
__global__ void pre_kernel(const float* __restrict__ pred, const int* __restrict__ inst,
                           const int* __restrict__ lab, float* __restrict__ stats,
                           float* __restrict__ seedbg, float2* __restrict__ exy) {
  __shared__ float ls[4][NID * 7];     // per-wave private stats copies
  int tid = threadIdx.x;
  int w = tid >> 6, lane = tid & 63;
  for (int i = tid; i < 4 * NID * 7; i += 256) ((float*)ls)[i] = 0.f;
  __syncthreads();
  int b = blockIdx.y;
  const float* pb = pred + (size_t)b * 5 * HW;
  float bgacc = 0.f;
  for (int i = blockIdx.x * 256 + tid; i < HW; i += gridDim.x * 256) {
    float p0 = pb[i], p1 = pb[HW + i], p2 = pb[2 * HW + i], p3 = pb[3 * HW + i], p4 = pb[4 * HW + i];
    float xm = (float)(i & 511) * (1.0f / 511.0f);
    float ym = (float)(i >> 9) * (1.0f / 511.0f);
    float ex = tanhf(p0) + xm;
    float ey = tanhf(p1) + ym;
    exy[(size_t)b * HW + i] = make_float2(ex, ey);
    int t = inst[(size_t)b * HW + i];
    if (t >= 1 && t <= NID) {
      float* s = ls[w] + (t - 1) * 7;
      atomicAdd(s + 0, 1.0f);
      atomicAdd(s + 1, ex);
      atomicAdd(s + 2, ey);
      atomicAdd(s + 3, p2);
      atomicAdd(s + 4, p3);
      atomicAdd(s + 5, p2 * p2);
      atomicAdd(s + 6, p3 * p3);
    }
    if (lab[(size_t)b * HW + i] == 0) {
      float sd = 1.0f / (1.0f + expf(-p4));
      bgacc += sd * sd;        // register accumulation, no atomic
    }
  }
  for (int off = 32; off > 0; off >>= 1) bgacc += __shfl_down(bgacc, off, 64);
  __syncthreads();
  for (int i = tid; i < NID * 7; i += 256) {
    float v = ls[0][i] + ls[1][i] + ls[2][i] + ls[3][i];
    int id = i / 7, s = i % 7;
    atomicAdd(&stats[(b * NID + id) * 8 + s], v);
  }
  if (lane == 0 && bgacc != 0.f) atomicAdd(&seedbg[b], bgacc);
}

// ---------------- derived per-(b,id) params ----------------
__global__ void derived_kernel(const float* __restrict__ stats, float* __restrict__ derived) {
  int i = blockIdx.x * 256 + threadIdx.x;
  if (i >= NSEG) return;
  const float* st = stats + i * 8;
  float cnt = st[0];
  float safe = fmaxf(cnt, 1.0f);
  float cx = st[1] / safe, cy = st[2] / safe;
  float m0 = st[3] / safe, m1 = st[4] / safe;
  float v0 = st[5] - 2.0f * m0 * (m0 * safe) + m0 * m0 * cnt;
  float v1 = st[6] - 2.0f * m1 * (m1 * safe) + m1 * m1 * cnt;
  float vi = (v0 + v1) / (2.0f * safe);
  float* dd = derived + i * 8;
  dd[0] = cx;
  dd[1] = cy;
  dd[2] = expf(10.0f * m0);
  dd[3] = expf(10.0f * m1);
  dd[4] = vi;
  dd[5] = (cnt > 0.f) ? 1.f : 0.f;
  dd[6] = cnt;
  dd[7] = 0.f;
}

// ---------------- phase 1: split per-segment LDS histograms -> global ushort partials ----------------
__global__ void __launch_bounds__(S1T)
hist_kernel(const float2* __restrict__ exy, const float* __restrict__ pred,
            const int* __restrict__ inst, const float* __restrict__ derived,
            unsigned short* __restrict__ partP, unsigned short* __restrict__ partN,
            float* __restrict__ seedi) {
  int bid = blockIdx.x;
  int seg = bid / NSPL, split = bid % NSPL;
  int b = seg / NID, n = seg % NID;
  __shared__ int histP[KTOT];
  __shared__ int histN[KTOT];
  __shared__ float prm[8];
  int tid = threadIdx.x;
  if (tid < 8) prm[tid] = derived[(size_t)seg * 8 + tid];
  for (int k = tid; k < KTOT; k += S1T) { histP[k] = 0; histN[k] = 0; }
  __syncthreads();
  if (prm[5] == 0.f) return;   // invalid segment: partials never read
  float cx = prm[0], cy = prm[1], e0 = prm[2], e1 = prm[3];
  const float2* eb = exy + (size_t)b * HW;
  const int* ib = inst + (size_t)b * HW;
  const float* p4b = pred + ((size_t)b * 5 + 4) * HW;
  int base = split * (HW / NSPL);
  int lane = tid & 63;
  int woff = tid & ~63;
  int swl = (lane * 21) & 63;       // decorrelate bucket keys within a wave
  float sacc = 0.f;
  for (int it = 0; it < HW / NSPL; it += S1T) {
    int i = base + it + woff + swl;
    float2 e = eb[i];
    int t = ib[i];
    float dx = e.x - cx;
    float dy = e.y - cy;
    float d = expf(-(e0 * dx * dx + e1 * dy * dy));
    int k = keyof(d);
    if (t == n + 1) {
      atomicAdd(&histP[k], 1);
      float sd = 1.0f / (1.0f + expf(-p4b[i]));
      float df = sd - d;
      sacc += df * df;
    } else {
      atomicAdd(&histN[k], 1);
    }
  }
  for (int off = 32; off > 0; off >>= 1) sacc += __shfl_down(sacc, off, 64);
  if (lane == 0 && sacc != 0.f) atomicAdd(&seedi[seg], sacc);
  __syncthreads();
  size_t pb = (size_t)bid * KTOT;
  for (int k = tid; k < KTOT; k += S1T) {
    partP[pb + k] = (unsigned short)histP[k];   // max 65536/bucket impossible for real data
    partN[pb + k] = (unsigned short)histN[k];
  }
}

// ---------------- phase 2+3: combine partials, LDS scans, bucket-sweep Lovasz ----------------
__global__ void __launch_bounds__(1024)
lovasz_kernel(const unsigned short* __restrict__ partP, const unsigned short* __restrict__ partN,
              const float* __restrict__ derived, float* __restrict__ instAcc) {
  __shared__ int histP[KTOT];
  __shared__ int histN[KTOT];
  __shared__ int PreP[KTOT + 1];
  __shared__ int PreN[KTOT + 1];
  __shared__ int scr[1024];
  __shared__ float prm[8];
  int seg = blockIdx.x;
  int tid = threadIdx.x;
  if (tid < 8) prm[tid] = derived[(size_t)seg * 8 + tid];
  __syncthreads();
  if (prm[5] == 0.f) {
    if (tid == 0) instAcc[seg] = 0.f;
    return;
  }
  int P = (int)prm[6];
  int Nn = HW - P;
  for (int k = tid; k < KTOT; k += 1024) {
    int sp = 0, sn = 0;
#pragma unroll
    for (int s = 0; s < NSPL; ++s) {
      size_t pb = (size_t)(seg * NSPL + s) * KTOT;
      sp += partP[pb + k];
      sn += partN[pb + k];
    }
    histP[k] = sp;
    histN[k] = sn;
  }
  __syncthreads();
  // exclusive prefix sums over keys (pos then neg)
  {
    int base = tid * 3;
    int a0 = (base < KTOT) ? histP[base] : 0;
    int a1 = (base + 1 < KTOT) ? histP[base + 1] : 0;
    int a2 = (base + 2 < KTOT) ? histP[base + 2] : 0;
    scr[tid] = a0 + a1 + a2;
    __syncthreads();
    for (int off = 1; off < 1024; off <<= 1) {
      int v = scr[tid];
      int u = (tid >= off) ? scr[tid - off] : 0;
      __syncthreads();
      scr[tid] = v + u;
      __syncthreads();
    }
    int excl = (tid > 0) ? scr[tid - 1] : 0;
    if (base < KTOT) PreP[base] = excl;
    if (base + 1 < KTOT) PreP[base + 1] = excl + a0;
    if (base + 2 < KTOT) PreP[base + 2] = excl + a0 + a1;
    if (tid == 0) PreP[KTOT] = scr[1023];
    __syncthreads();
    a0 = (base < KTOT) ? histN[base] : 0;
    a1 = (base + 1 < KTOT) ? histN[base + 1] : 0;
    a2 = (base + 2 < KTOT) ? histN[base + 2] : 0;
    scr[tid] = a0 + a1 + a2;
    __syncthreads();
    for (int off = 1; off < 1024; off <<= 1) {
      int v = scr[tid];
      int u = (tid >= off) ? scr[tid - off] : 0;
      __syncthreads();
      scr[tid] = v + u;
      __syncthreads();
    }
    excl = (tid > 0) ? scr[tid - 1] : 0;
    if (base < KTOT) PreN[base] = excl;
    if (base + 1 < KTOT) PreN[base + 1] = excl + a0;
    if (base + 2 < KTOT) PreN[base + 2] = excl + a0 + a1;
    if (tid == 0) PreN[KTOT] = scr[1023];
    __syncthreads();
  }
  // per-bucket closed-form Lovasz contributions
  float acc = 0.f;
  for (int k = tid; k < KTOT; k += 1024) {
    int hp = histP[k], hn = histN[k];
    if ((hp | hn) == 0) continue;
    float lo, hi;
    boundsof(k, &lo, &hi);
    float m = 0.5f * (lo + hi);
    m = fminf(m, __uint_as_float(0x3F7FFFFFu));
    float tv = 1.0f - m;
    int j = keyof(tv);
    float jlo, jhi;
    boundsof(j, &jlo, &jhi);
    float den = jhi - jlo;
    float fr = (den > 0.f) ? (tv - jlo) / den : 0.5f;
    fr = fminf(fmaxf(fr, 0.f), 1.f);
    if (hp) {
      float q = (float)(Nn - PreN[j + 1]) + (1.0f - fr) * (float)histN[j];
      float a = 2.0f - 2.0f * m;
      acc += (float)hp * a / ((float)P + q);
    }
    if (hn) {
      float p = (float)PreP[j] + fr * (float)histP[j];
      int R = Nn - PreN[k + 1];
      float u0 = 1.0f / (float)(P + R);
      float u1 = 1.0f / (float)(P + R + hn);
      acc += (2.0f * m) * ((float)P - p) * (u0 - u1);
    }
  }
  float* scrf = (float*)scr;
  scrf[tid] = acc;
  __syncthreads();
  for (int s = 512; s > 0; s >>= 1) {
    if (tid < s) scrf[tid] += scrf[tid + s];
    __syncthreads();
  }
  if (tid == 0) instAcc[seg] = scrf[0];
}

// ---------------- final combine ----------------
__global__ void final_kernel(const float* __restrict__ derived, const float* __restrict__ instAcc,
                             const float* __restrict__ seediAcc, const float* __restrict__ seedbg,
                             float* __restrict__ out) {
  int b = threadIdx.x;
  __shared__ float red[64];
  float lb = 0.f;
  if (b < BATCH) {
    float sv = 0.f, si = 0.f, svar = 0.f, ssd = 0.f;
    for (int n = 0; n < NID; ++n) {
      const float* dd = derived + (b * NID + n) * 8;
      float vf = dd[5];
      sv += vf;
      si += vf * instAcc[b * NID + n];
      svar += vf * dd[4];
      ssd += vf * seediAcc[b * NID + n];
    }
    float obj = fmaxf(sv, 1.0f);
    lb = si / obj + 10.0f * (svar / obj) + (seedbg[b] + ssd) / (float)HW;
  }
  red[threadIdx.x] = lb;
  __syncthreads();
  for (int s = 32; s > 0; s >>= 1) {
    if (threadIdx.x < s) red[threadIdx.x] += red[threadIdx.x + s];
    __syncthreads();
  }
  if (threadIdx.x == 0) out[0] = red[0] / (float)BATCH;
}

extern "C" void kernel_launch(void* const* d_in, const int* in_sizes, int n_in,
                              void* d_out, int out_size, void* d_ws, size_t ws_size,
                              hipStream_t stream) {
  const float* pred = (const float*)d_in[0];
  const int* inst = (const int*)d_in[1];
  const int* lab = (const int*)d_in[2];
  float* out = (float*)d_out;

  // head (floats): stats[1920] derived[1920] instAcc[240] seedi[240] seedbg[16]
  float* wsf = (float*)d_ws;
  float* stats = wsf;
  float* derived = wsf + 1920;
  float* instAcc = wsf + 3840;
  float* seediAcc = wsf + 4080;
  float* seedbg = wsf + 4320;
  float2* exy = (float2*)((char*)d_ws + HEADB);                  // 16*HW*8B = 33.55 MB
  unsigned short* partP = (unsigned short*)((char*)d_ws + HEADB + (size_t)BATCH * HW * 8);
  unsigned short* partN = partP + (size_t)NSEG * NSPL * KTOT;    // 2 * 4.65 MB
  // total: 64 KB + 33.55 MB + 9.31 MB = 42.9 MB (< proven-safe 50.46 MB)

  hipMemsetAsync(d_ws, 0, HEADB, stream);
  pre_kernel<<<dim3(64, BATCH), 256, 0, stream>>>(pred, inst, lab, stats, seedbg, exy);
  derived_kernel<<<1, 256, 0, stream>>>(stats, derived);
  hist_kernel<<<NSEG * NSPL, S1T, 0, stream>>>(exy, pred, inst, derived, partP, partN, seediAcc);
  lovasz_kernel<<<NSEG, 1024, 0, stream>>>(partP, partN, derived, instAcc);
  final_kernel<<<1, 64, 0, stream>>>(derived, instAcc, seediAcc, seedbg, out);
}

// Round 5
// 343.486 us; speedup vs baseline: 26.9038x; 1.1735x over previous
//
#include <hip/hip_runtime.h>
#include <hip/hip_fp16.h>
#include <cmath>

#define BATCH 16
#define NID   15
#define NSEG  240
#define HW    262144          // 512*512
#define HEADB 65536
#define NSPL  4               // hist blocks per segment
#define S1T   512             // hist block threads
#define PREBLK 4096           // pre blocks (256 per batch, 1024 px each)
#define PSTRIDE 112           // floats per pre-block partial record (105 stats + 1 bg + pad)

// compact key space for d = exp(-arg) in [0,1]:
//   d >= 2^-8 : fine buckets (float_bits>>15), 2305 keys, ~0.39% relative width
//   d <  2^-8 : exponent-only buckets (float_bits>>23), 119 keys
#define KFINEBASE 30208       // 0x3B800000 >> 15
#define KOVF 119
#define KTOT 2424             // 119 + 2305

__device__ __forceinline__ int keyof(float d) {
  unsigned b = __float_as_uint(d);
  return (b >= 0x3B800000u) ? (int)((b >> 15) - KFINEBASE + KOVF) : (int)(b >> 23);
}
__device__ __forceinline__ void boundsof(int k, float* lo, float* hi) {
  if (k >= KOVF) {
    unsigned u = (unsigned)(k - KOVF + KFINEBASE) << 15;
    *lo = __uint_as_float(u);
    *hi = __uint_as_float(u + 32768u);
  } else {
    *lo = __uint_as_float((unsigned)k << 23);
    *hi = __uint_as_float((unsigned)(k + 1) << 23);
  }
}

// ---------------- pre: vectorized transform + per-block stat partials + packed records ----------------
__global__ void __launch_bounds__(256)
pre_kernel(const float* __restrict__ pred, const int* __restrict__ inst,
           const int* __restrict__ lab, float* __restrict__ blockpart,
           unsigned* __restrict__ exyh, unsigned* __restrict__ tb8,
           unsigned* __restrict__ sd8) {
  __shared__ float ls[4][NID * 7];
  __shared__ float lbg[4];
  int tid = threadIdx.x;
  int w = tid >> 6, lane = tid & 63;
  for (int i = tid; i < 4 * NID * 7; i += 256) ((float*)ls)[i] = 0.f;
  __syncthreads();
  int gid = blockIdx.x;
  int b = gid >> 8, c = gid & 255;     // 256 blocks per batch, 1024 px per block
  const float* pb = pred + (size_t)b * 5 * HW;
  int i4 = c * 256 + tid;              // float4 index within batch
  float4 v0 = ((const float4*)pb)[i4];
  float4 v1 = ((const float4*)(pb + HW))[i4];
  float4 v2 = ((const float4*)(pb + 2 * HW))[i4];
  float4 v3 = ((const float4*)(pb + 3 * HW))[i4];
  float4 v4 = ((const float4*)(pb + 4 * HW))[i4];
  int4 t4 = ((const int4*)(inst + (size_t)b * HW))[i4];
  int4 l4 = ((const int4*)(lab + (size_t)b * HW))[i4];
  int px0 = i4 * 4;
  float bgacc = 0.f;
  unsigned eo[4], tpack = 0, spack = 0;
  float p0a[4] = {v0.x, v0.y, v0.z, v0.w};
  float p1a[4] = {v1.x, v1.y, v1.z, v1.w};
  float p2a[4] = {v2.x, v2.y, v2.z, v2.w};
  float p3a[4] = {v3.x, v3.y, v3.z, v3.w};
  float p4a[4] = {v4.x, v4.y, v4.z, v4.w};
  int ta[4] = {t4.x, t4.y, t4.z, t4.w};
  int la[4] = {l4.x, l4.y, l4.z, l4.w};
#pragma unroll
  for (int k = 0; k < 4; ++k) {
    int px = px0 + k;
    float xm = (float)(px & 511) * (1.0f / 511.0f);
    float ym = (float)(px >> 9) * (1.0f / 511.0f);
    float ex = tanhf(p0a[k]) + xm;
    float ey = tanhf(p1a[k]) + ym;
    float sd = 1.0f / (1.0f + expf(-p4a[k]));
    __half2 h = __floats2half2_rn(ex, ey);
    eo[k] = *reinterpret_cast<unsigned*>(&h);
    int t = ta[k];
    tpack |= ((unsigned)(t & 255)) << (8 * k);
    unsigned sq = (unsigned)(sd * 255.0f + 0.5f);
    spack |= (sq & 255u) << (8 * k);
    if (t >= 1 && t <= NID) {
      float* s = ls[w] + (t - 1) * 7;
      atomicAdd(s + 0, 1.0f);
      atomicAdd(s + 1, ex);
      atomicAdd(s + 2, ey);
      atomicAdd(s + 3, p2a[k]);
      atomicAdd(s + 4, p3a[k]);
      atomicAdd(s + 5, p2a[k] * p2a[k]);
      atomicAdd(s + 6, p3a[k] * p3a[k]);
    }
    if (la[k] == 0) bgacc += sd * sd;
  }
  size_t obase = (size_t)b * (HW / 4) + i4;
  ((uint4*)exyh)[obase / 4 * 0] = make_uint4(0, 0, 0, 0);  // placeholder removed below
  // packed stores
  {
    uint4 e4 = make_uint4(eo[0], eo[1], eo[2], eo[3]);
    ((uint4*)exyh)[(size_t)b * (HW / 4) + i4] = e4;
    tb8[(size_t)b * (HW / 4) + i4] = tpack;
    sd8[(size_t)b * (HW / 4) + i4] = spack;
  }
  for (int off = 32; off > 0; off >>= 1) bgacc += __shfl_down(bgacc, off, 64);
  if (lane == 0) lbg[w] = bgacc;
  __syncthreads();
  float* bp = blockpart + (size_t)gid * PSTRIDE;
  for (int i = tid; i < NID * 7; i += 256)
    bp[i] = ls[0][i] + ls[1][i] + ls[2][i] + ls[3][i];
  if (tid == 0) bp[NID * 7] = lbg[0] + lbg[1] + lbg[2] + lbg[3];
}

// ---------------- reduce pre partials -> stats, seedbg ----------------
__global__ void reduce_kernel(const float* __restrict__ blockpart, float* __restrict__ stats,
                              float* __restrict__ seedbg) {
  int s = blockIdx.x;       // 0..105
  int b = blockIdx.y;
  int tid = threadIdx.x;    // 256 = blocks per batch
  float v = blockpart[(size_t)(b * 256 + tid) * PSTRIDE + s];
  for (int off = 32; off > 0; off >>= 1) v += __shfl_down(v, off, 64);
  __shared__ float red[4];
  if ((tid & 63) == 0) red[tid >> 6] = v;
  __syncthreads();
  if (tid == 0) {
    float tot = red[0] + red[1] + red[2] + red[3];
    if (s < NID * 7) {
      int id = s / 7, st = s % 7;
      stats[(b * NID + id) * 8 + st] = tot;
    } else {
      seedbg[b] = tot;
    }
  }
}

// ---------------- derived per-(b,id) params ----------------
__global__ void derived_kernel(const float* __restrict__ stats, float* __restrict__ derived) {
  int i = blockIdx.x * 256 + threadIdx.x;
  if (i >= NSEG) return;
  const float* st = stats + i * 8;
  float cnt = st[0];
  float safe = fmaxf(cnt, 1.0f);
  float cx = st[1] / safe, cy = st[2] / safe;
  float m0 = st[3] / safe, m1 = st[4] / safe;
  float v0 = st[5] - 2.0f * m0 * (m0 * safe) + m0 * m0 * cnt;
  float v1 = st[6] - 2.0f * m1 * (m1 * safe) + m1 * m1 * cnt;
  float vi = (v0 + v1) / (2.0f * safe);
  float* dd = derived + i * 8;
  dd[0] = cx;
  dd[1] = cy;
  dd[2] = expf(10.0f * m0);
  dd[3] = expf(10.0f * m1);
  dd[4] = vi;
  dd[5] = (cnt > 0.f) ? 1.f : 0.f;
  dd[6] = cnt;
  dd[7] = 0.f;
}

// ---------------- phase 1: split per-segment LDS histograms from packed records ----------------
__global__ void __launch_bounds__(S1T)
hist_kernel(const unsigned* __restrict__ exyh, const unsigned* __restrict__ tb8,
            const unsigned* __restrict__ sd8, const float* __restrict__ derived,
            unsigned short* __restrict__ partP, unsigned short* __restrict__ partN,
            float* __restrict__ seedi) {
  int bid = blockIdx.x;
  int seg = bid / NSPL, split = bid % NSPL;
  int b = seg / NID, n = seg % NID;
  __shared__ int histP[KTOT];
  __shared__ int histN[KTOT];
  __shared__ float prm[8];
  int tid = threadIdx.x;
  if (tid < 8) prm[tid] = derived[(size_t)seg * 8 + tid];
  for (int k = tid; k < KTOT; k += S1T) { histP[k] = 0; histN[k] = 0; }
  __syncthreads();
  if (prm[5] == 0.f) return;   // invalid segment: partials never read
  float cx = prm[0], cy = prm[1], e0 = prm[2], e1 = prm[3];
  const uint4* ev = (const uint4*)(exyh + (size_t)b * (HW / 4));  // 16 px per uint4
  const unsigned* tv = tb8 + (size_t)b * (HW / 4);
  const unsigned* sv = sd8 + (size_t)b * (HW / 4);
  int lane = tid & 63;
  int wid = tid >> 6;               // 8 waves
  int swl = (lane * 21) & 63;       // decorrelate bucket keys within a wave
  float sacc = 0.f;
  // split covers quarter of px: groups of 4 px; 16384 groups per split; 2048 per pass
  for (int it = 0; it < 32; ++it) {
    int g = split * 16384 + it * 512 + wid * 64 + swl;    // 4-px group index
    uint4 e4 = ev[g >> 2 << 2 | 0];  // dummy to keep alignment thinking simple
    // proper: load the uint at group g from exyh via 16B chunks is overkill; load scalar uint4 per 4 groups
    // simpler path: scalar loads
    (void)e4;
    unsigned tp = tv[g];
    unsigned sp = sv[g];
    unsigned ew[4];
    {
      const uint4* evg = (const uint4*)(exyh + (size_t)b * (HW / 4));
      uint4 ee = evg[g];             // 4 px of packed half2 (16 B)
      ew[0] = ee.x; ew[1] = ee.y; ew[2] = ee.z; ew[3] = ee.w;
    }
#pragma unroll
    for (int k = 0; k < 4; ++k) {
      unsigned u = ew[k];
      __half2 h = *reinterpret_cast<__half2*>(&u);
      float2 e = __half22float2(h);
      float dx = e.x - cx;
      float dy = e.y - cy;
      float d = expf(-(e0 * dx * dx + e1 * dy * dy));
      int key = keyof(d);
      int t = (int)((tp >> (8 * k)) & 255u);
      if (t == n + 1) {
        atomicAdd(&histP[key], 1);
        float sd = (float)((sp >> (8 * k)) & 255u) * (1.0f / 255.0f);
        float df = sd - d;
        sacc += df * df;
      } else {
        atomicAdd(&histN[key], 1);
      }
    }
  }
  for (int off = 32; off > 0; off >>= 1) sacc += __shfl_down(sacc, off, 64);
  if (lane == 0 && sacc != 0.f) atomicAdd(&seedi[seg], sacc);
  __syncthreads();
  size_t pb = (size_t)bid * KTOT;
  for (int k = tid; k < KTOT; k += S1T) {
    partP[pb + k] = (unsigned short)histP[k];
    partN[pb + k] = (unsigned short)histN[k];
  }
}

// ---------------- phase 2+3: combine partials, LDS scans, bucket-sweep Lovasz ----------------
__global__ void __launch_bounds__(1024)
lovasz_kernel(const unsigned short* __restrict__ partP, const unsigned short* __restrict__ partN,
              const float* __restrict__ derived, float* __restrict__ instAcc) {
  __shared__ int histP[KTOT];
  __shared__ int histN[KTOT];
  __shared__ int PreP[KTOT + 1];
  __shared__ int PreN[KTOT + 1];
  __shared__ int scr[1024];
  __shared__ float prm[8];
  int seg = blockIdx.x;
  int tid = threadIdx.x;
  if (tid < 8) prm[tid] = derived[(size_t)seg * 8 + tid];
  __syncthreads();
  if (prm[5] == 0.f) {
    if (tid == 0) instAcc[seg] = 0.f;
    return;
  }
  int P = (int)prm[6];
  int Nn = HW - P;
  for (int k = tid; k < KTOT; k += 1024) {
    int sp = 0, sn = 0;
#pragma unroll
    for (int s = 0; s < NSPL; ++s) {
      size_t pb = (size_t)(seg * NSPL + s) * KTOT;
      sp += partP[pb + k];
      sn += partN[pb + k];
    }
    histP[k] = sp;
    histN[k] = sn;
  }
  __syncthreads();
  {
    int base = tid * 3;
    int a0 = (base < KTOT) ? histP[base] : 0;
    int a1 = (base + 1 < KTOT) ? histP[base + 1] : 0;
    int a2 = (base + 2 < KTOT) ? histP[base + 2] : 0;
    scr[tid] = a0 + a1 + a2;
    __syncthreads();
    for (int off = 1; off < 1024; off <<= 1) {
      int v = scr[tid];
      int u = (tid >= off) ? scr[tid - off] : 0;
      __syncthreads();
      scr[tid] = v + u;
      __syncthreads();
    }
    int excl = (tid > 0) ? scr[tid - 1] : 0;
    if (base < KTOT) PreP[base] = excl;
    if (base + 1 < KTOT) PreP[base + 1] = excl + a0;
    if (base + 2 < KTOT) PreP[base + 2] = excl + a0 + a1;
    if (tid == 0) PreP[KTOT] = scr[1023];
    __syncthreads();
    a0 = (base < KTOT) ? histN[base] : 0;
    a1 = (base + 1 < KTOT) ? histN[base + 1] : 0;
    a2 = (base + 2 < KTOT) ? histN[base + 2] : 0;
    scr[tid] = a0 + a1 + a2;
    __syncthreads();
    for (int off = 1; off < 1024; off <<= 1) {
      int v = scr[tid];
      int u = (tid >= off) ? scr[tid - off] : 0;
      __syncthreads();
      scr[tid] = v + u;
      __syncthreads();
    }
    excl = (tid > 0) ? scr[tid - 1] : 0;
    if (base < KTOT) PreN[base] = excl;
    if (base + 1 < KTOT) PreN[base + 1] = excl + a0;
    if (base + 2 < KTOT) PreN[base + 2] = excl + a0 + a1;
    if (tid == 0) PreN[KTOT] = scr[1023];
    __syncthreads();
  }
  float acc = 0.f;
  for (int k = tid; k < KTOT; k += 1024) {
    int hp = histP[k], hn = histN[k];
    if ((hp | hn) == 0) continue;
    float lo, hi;
    boundsof(k, &lo, &hi);
    float m = 0.5f * (lo + hi);
    m = fminf(m, __uint_as_float(0x3F7FFFFFu));
    float tv = 1.0f - m;
    int j = keyof(tv);
    float jlo, jhi;
    boundsof(j, &jlo, &jhi);
    float den = jhi - jlo;
    float fr = (den > 0.f) ? (tv - jlo) / den : 0.5f;
    fr = fminf(fmaxf(fr, 0.f), 1.f);
    if (hp) {
      float q = (float)(Nn - PreN[j + 1]) + (1.0f - fr) * (float)histN[j];
      float a = 2.0f - 2.0f * m;
      acc += (float)hp * a / ((float)P + q);
    }
    if (hn) {
      float p = (float)PreP[j] + fr * (float)histP[j];
      int R = Nn - PreN[k + 1];
      float u0 = 1.0f / (float)(P + R);
      float u1 = 1.0f / (float)(P + R + hn);
      acc += (2.0f * m) * ((float)P - p) * (u0 - u1);
    }
  }
  float* scrf = (float*)scr;
  scrf[tid] = acc;
  __syncthreads();
  for (int s = 512; s > 0; s >>= 1) {
    if (tid < s) scrf[tid] += scrf[tid + s];
    __syncthreads();
  }
  if (tid == 0) instAcc[seg] = scrf[0];
}

// ---------------- final combine ----------------
__global__ void final_kernel(const float* __restrict__ derived, const float* __restrict__ instAcc,
                             const float* __restrict__ seediAcc, const float* __restrict__ seedbg,
                             float* __restrict__ out) {
  int b = threadIdx.x;
  __shared__ float red[64];
  float lb = 0.f;
  if (b < BATCH) {
    float sv = 0.f, si = 0.f, svar = 0.f, ssd = 0.f;
    for (int n = 0; n < NID; ++n) {
      const float* dd = derived + (b * NID + n) * 8;
      float vf = dd[5];
      sv += vf;
      si += vf * instAcc[b * NID + n];
      svar += vf * dd[4];
      ssd += vf * seediAcc[b * NID + n];
    }
    float obj = fmaxf(sv, 1.0f);
    lb = si / obj + 10.0f * (svar / obj) + (seedbg[b] + ssd) / (float)HW;
  }
  red[threadIdx.x] = lb;
  __syncthreads();
  for (int s = 32; s > 0; s >>= 1) {
    if (threadIdx.x < s) red[threadIdx.x] += red[threadIdx.x + s];
    __syncthreads();
  }
  if (threadIdx.x == 0) out[0] = red[0] / (float)BATCH;
}

extern "C" void kernel_launch(void* const* d_in, const int* in_sizes, int n_in,
                              void* d_out, int out_size, void* d_ws, size_t ws_size,
                              hipStream_t stream) {
  const float* pred = (const float*)d_in[0];
  const int* inst = (const int*)d_in[1];
  const int* lab = (const int*)d_in[2];
  float* out = (float*)d_out;

  // head (floats): stats[1920] derived[1920] instAcc[240] seedi[240] seedbg[16]
  float* wsf = (float*)d_ws;
  float* stats = wsf;
  float* derived = wsf + 1920;
  float* instAcc = wsf + 3840;
  float* seediAcc = wsf + 4080;
  float* seedbg = wsf + 4320;
  char* p = (char*)d_ws + HEADB;
  unsigned* exyh = (unsigned*)p;                 p += (size_t)BATCH * HW * 4;       // 16.78 MB
  unsigned* tb8 = (unsigned*)p;                  p += (size_t)BATCH * HW;           // 4.19 MB
  unsigned* sd8 = (unsigned*)p;                  p += (size_t)BATCH * HW;           // 4.19 MB
  unsigned short* partP = (unsigned short*)p;    p += (size_t)NSEG * NSPL * KTOT * 2; // 4.65 MB
  unsigned short* partN = (unsigned short*)p;    p += (size_t)NSEG * NSPL * KTOT * 2; // 4.65 MB
  float* blockpart = (float*)p;                  // 4096*112*4 = 1.84 MB; total ~36.4 MB

  hipMemsetAsync(d_ws, 0, HEADB, stream);
  pre_kernel<<<PREBLK, 256, 0, stream>>>(pred, inst, lab, blockpart, exyh, tb8, sd8);
  reduce_kernel<<<dim3(NID * 7 + 1, BATCH), 256, 0, stream>>>(blockpart, stats, seedbg);
  derived_kernel<<<1, 256, 0, stream>>>(stats, derived);
  hist_kernel<<<NSEG * NSPL, S1T, 0, stream>>>(exyh, tb8, sd8, derived, partP, partN, seediAcc);
  lovasz_kernel<<<NSEG, 1024, 0, stream>>>(partP, partN, derived, instAcc);
  final_kernel<<<1, 64, 0, stream>>>(derived, instAcc, seediAcc, seedbg, out);
}